// Round 5
// baseline (571.847 us; speedup 1.0000x reference)
//
#include <hip/hip_runtime.h>
#include <cstdint>
#include <cstddef>

typedef __bf16 bf16_t;
typedef __bf16 bf16x4 __attribute__((ext_vector_type(4)));
typedef __bf16 bf16x8 __attribute__((ext_vector_type(8)));
typedef float f32x4 __attribute__((ext_vector_type(4)));

#define B_ 4
#define T_ 2048
#define DIM_ 2048
#define H_ 16
#define KVH_ 4
#define HD_ 128
#define QKV_ 3072
// SCALE * log2(e): folded into q rows in the gemm_qkv epilogue; attn uses exp2.
#define QSCALE (0.08838834764831845f * 1.4426950408889634f)

// ---------------------------------------------------------------------------
// async global->LDS, 16B per lane. LDS dest = wave-uniform base + lane*16B.
// Dest pointer arithmetic is in ELEMENTS: 8 bf16 = 16B per lane.
// ---------------------------------------------------------------------------
__device__ __forceinline__ void gload16(const bf16_t* g, bf16_t* l) {
  __builtin_amdgcn_global_load_lds(
      (const __attribute__((address_space(1))) unsigned int*)g,
      (__attribute__((address_space(3))) unsigned int*)l, 16, 0, 0);
}

// ---------------------------------------------------------------------------
// fused fp32 -> bf16 convert for all five inputs (one launch).
// Segments (float4 units): x 4194304 | Wq 1048576 | Wk 262144 | Wv 262144 | Wp 1048576
// ---------------------------------------------------------------------------
__global__ __launch_bounds__(256) void cvt_all(const float4* __restrict__ x,
                                               const float4* __restrict__ wq,
                                               const float4* __restrict__ wk,
                                               const float4* __restrict__ wv,
                                               const float4* __restrict__ wp,
                                               bf16x4* __restrict__ xb,
                                               bf16x4* __restrict__ wqkvb,
                                               bf16x4* __restrict__ wpb) {
  int i = blockIdx.x * 256 + threadIdx.x;
  const float4* s;
  bf16x4* dst;
  int off;
  if (i < 4194304) { s = x; dst = xb; off = i; }
  else if (i < 5242880) { s = wq; dst = wqkvb; off = i - 4194304; }
  else if (i < 5505024) { s = wk; dst = wqkvb + 1048576; off = i - 5242880; }
  else if (i < 5767168) { s = wv; dst = wqkvb + 1310720; off = i - 5505024; }
  else { s = wp; dst = wpb; off = i - 5767168; }
  float4 v = s[off];
  bf16x4 o = {(__bf16)v.x, (__bf16)v.y, (__bf16)v.z, (__bf16)v.w};
  dst[off] = o;
}

// ---------------------------------------------------------------------------
// GEMM: C(MxN) = A(MxK) @ B(NxK)^T, bf16 in, fp32 acc.
// R5: attn-style software pipeline -- double-buffered LDS, per iteration:
// [syncthreads: drains tile-kk loads issued one iter ago] -> [issue tile
// kk+1 into other buffer] -> [compute tile kk]. The barrier's vmcnt(0)
// then only covers loads that had a full compute phase to land (m97's
// stage->drain->compute waited full HBM latency every iter; MfmaUtil was
// 20.5%). One barrier/iter instead of two.
// ---------------------------------------------------------------------------
__global__ __launch_bounds__(256) void gemm_bt(const bf16_t* __restrict__ A,
                                               const bf16_t* __restrict__ B,
                                               void* __restrict__ Cp,
                                               int M, int N, int K, int out_bf16) {
  __shared__ bf16_t As[2][128 * 32];
  __shared__ bf16_t Bs[2][128 * 32];
  const int tid = threadIdx.x;
  const int w = tid >> 6, lane = tid & 63;
  const int m_lane = lane & 15, quad = lane >> 4;
  const int wr = w >> 1, wc = w & 1;
  const int rowBase = blockIdx.y * 128, colBase = blockIdx.x * 128;

  // per-thread staging indices: idx in {tid, 256+tid}, row=idx>>2, kc=idx&3
  const int r0 = tid >> 2, c0 = tid & 3;
  const int r1 = (256 + tid) >> 2, c1 = tid & 3;

  f32x4 acc[4][4];
#pragma unroll
  for (int i = 0; i < 4; ++i)
#pragma unroll
    for (int j = 0; j < 4; ++j) acc[i][j] = (f32x4){0.f, 0.f, 0.f, 0.f};

  // prologue: stage tile 0 into buffer 0
  gload16(A + (size_t)(rowBase + r0) * K + c0 * 8, &As[0][tid * 8]);
  gload16(B + (size_t)(colBase + r0) * K + c0 * 8, &Bs[0][tid * 8]);
  gload16(A + (size_t)(rowBase + r1) * K + c1 * 8, &As[0][(256 + tid) * 8]);
  gload16(B + (size_t)(colBase + r1) * K + c1 * 8, &Bs[0][(256 + tid) * 8]);

  const int nk = K >> 5;
  for (int kk = 0; kk < nk; ++kk) {
    __syncthreads();  // drains tile-kk loads (issued one full iter ago)
    if (kk + 1 < nk) {
      const int k0 = (kk + 1) << 5;
      bf16_t* Ad = As[(kk + 1) & 1];
      bf16_t* Bd = Bs[(kk + 1) & 1];
      gload16(A + (size_t)(rowBase + r0) * K + k0 + c0 * 8, &Ad[tid * 8]);
      gload16(B + (size_t)(colBase + r0) * K + k0 + c0 * 8, &Bd[tid * 8]);
      gload16(A + (size_t)(rowBase + r1) * K + k0 + c1 * 8, &Ad[(256 + tid) * 8]);
      gload16(B + (size_t)(colBase + r1) * K + k0 + c1 * 8, &Bd[(256 + tid) * 8]);
    }
    const bf16_t* Ab = As[kk & 1];
    const bf16_t* Bb = Bs[kk & 1];
    bf16x8 a[4], bb[4];
#pragma unroll
    for (int i = 0; i < 4; ++i)
      a[i] = *(const bf16x8*)&Ab[(wr * 64 + i * 16 + m_lane) * 32 + quad * 8];
#pragma unroll
    for (int j = 0; j < 4; ++j)
      bb[j] = *(const bf16x8*)&Bb[(wc * 64 + j * 16 + m_lane) * 32 + quad * 8];
#pragma unroll
    for (int i = 0; i < 4; ++i)
#pragma unroll
      for (int j = 0; j < 4; ++j)
        acc[i][j] = __builtin_amdgcn_mfma_f32_16x16x32_bf16(a[i], bb[j], acc[i][j], 0, 0, 0);
  }

  if (out_bf16) {
    bf16_t* C = (bf16_t*)Cp;
#pragma unroll
    for (int i = 0; i < 4; ++i)
#pragma unroll
      for (int j = 0; j < 4; ++j)
#pragma unroll
        for (int r = 0; r < 4; ++r) {
          int row = rowBase + wr * 64 + i * 16 + quad * 4 + r;
          int col = colBase + wc * 64 + j * 16 + m_lane;
          C[(size_t)row * N + col] = (bf16_t)acc[i][j][r];
        }
  } else {
    float* C = (float*)Cp;
#pragma unroll
    for (int i = 0; i < 4; ++i)
#pragma unroll
      for (int j = 0; j < 4; ++j)
#pragma unroll
        for (int r = 0; r < 4; ++r) {
          int row = rowBase + wr * 64 + i * 16 + quad * 4 + r;
          int col = colBase + wc * 64 + j * 16 + m_lane;
          C[(size_t)row * N + col] = acc[i][j][r];
        }
  }
}

// ---------------------------------------------------------------------------
// QKV GEMM with fused epilogue: M=8192, N=3072, K=2048.
// Col-tile bx: 0..15 = q heads, 16..19 = k heads, 20..23 = v heads.
// q/k tiles: RMSNorm (fp32 acc, cross-wave LDS reduce) + RoPE (+gain*QSCALE
// for q). A 128-col tile is exactly one head; RoPE pairs (d,d+32) are
// lane-local (fragment j and j+2). v tiles: raw store + transposed store
// into vt (B,KVH,HD,T) -- replaces the separate vtrans kernel.
// R5: attn-style software pipeline (see gemm_bt header).
// ---------------------------------------------------------------------------
__global__ __launch_bounds__(256) void gemm_qkv(const bf16_t* __restrict__ A,
                                                const bf16_t* __restrict__ Bw,
                                                bf16_t* __restrict__ qkv,
                                                bf16_t* __restrict__ vt,
                                                const float* __restrict__ gain) {
  __shared__ bf16_t As[2][128 * 32];
  __shared__ bf16_t Bs[2][128 * 32];
  __shared__ float ssbuf[2][128];
  const int tid = threadIdx.x;
  const int w = tid >> 6, lane = tid & 63;
  const int m = lane & 15, quad = lane >> 4;
  const int wr = w >> 1, wc = w & 1;
  const int rowBase = blockIdx.y * 128, colBase = blockIdx.x * 128;

  const int r0 = tid >> 2, c0 = tid & 3;
  const int r1 = (256 + tid) >> 2, c1 = tid & 3;

  f32x4 acc[4][4];
#pragma unroll
  for (int i = 0; i < 4; ++i)
#pragma unroll
    for (int j = 0; j < 4; ++j) acc[i][j] = (f32x4){0.f, 0.f, 0.f, 0.f};

  // prologue: stage tile 0 into buffer 0
  gload16(A + (size_t)(rowBase + r0) * 2048 + c0 * 8, &As[0][tid * 8]);
  gload16(Bw + (size_t)(colBase + r0) * 2048 + c0 * 8, &Bs[0][tid * 8]);
  gload16(A + (size_t)(rowBase + r1) * 2048 + c1 * 8, &As[0][(256 + tid) * 8]);
  gload16(Bw + (size_t)(colBase + r1) * 2048 + c1 * 8, &Bs[0][(256 + tid) * 8]);

  for (int kk = 0; kk < 64; ++kk) {
    __syncthreads();  // drains tile-kk loads (issued one full iter ago)
    if (kk + 1 < 64) {
      const int k0 = (kk + 1) << 5;
      bf16_t* Ad = As[(kk + 1) & 1];
      bf16_t* Bd = Bs[(kk + 1) & 1];
      gload16(A + (size_t)(rowBase + r0) * 2048 + k0 + c0 * 8, &Ad[tid * 8]);
      gload16(Bw + (size_t)(colBase + r0) * 2048 + k0 + c0 * 8, &Bd[tid * 8]);
      gload16(A + (size_t)(rowBase + r1) * 2048 + k0 + c1 * 8, &Ad[(256 + tid) * 8]);
      gload16(Bw + (size_t)(colBase + r1) * 2048 + k0 + c1 * 8, &Bd[(256 + tid) * 8]);
    }
    const bf16_t* Ab = As[kk & 1];
    const bf16_t* Bb = Bs[kk & 1];
    bf16x8 a[4], bb[4];
#pragma unroll
    for (int i = 0; i < 4; ++i)
      a[i] = *(const bf16x8*)&Ab[(wr * 64 + i * 16 + m) * 32 + quad * 8];
#pragma unroll
    for (int j = 0; j < 4; ++j)
      bb[j] = *(const bf16x8*)&Bb[(wc * 64 + j * 16 + m) * 32 + quad * 8];
#pragma unroll
    for (int i = 0; i < 4; ++i)
#pragma unroll
      for (int j = 0; j < 4; ++j)
        acc[i][j] = __builtin_amdgcn_mfma_f32_16x16x32_bf16(a[i], bb[j], acc[i][j], 0, 0, 0);
  }

  const int bx = blockIdx.x;
  if (bx < 20) {
    // ---- q/k epilogue: RMSNorm + RoPE
    const float g = (bx < 16) ? gain[bx] * QSCALE : 1.0f;
    // per-row sum of squares: in-lane (4 cols) -> 16-lane tree -> LDS cross-wave
#pragma unroll
    for (int i = 0; i < 4; ++i) {
      float ssp[4];
#pragma unroll
      for (int r = 0; r < 4; ++r) {
        float s = 0.f;
#pragma unroll
        for (int j = 0; j < 4; ++j) s += acc[i][j][r] * acc[i][j][r];
#pragma unroll
        for (int off = 1; off <= 8; off <<= 1) s += __shfl_xor(s, off);
        ssp[r] = s;
      }
      if (m == 0) {
#pragma unroll
        for (int r = 0; r < 4; ++r) ssbuf[wc][wr * 64 + i * 16 + quad * 4 + r] = ssp[r];
      }
    }
    __syncthreads();
    // inv_freq for this lane's two rope pair-indices p=m and p=16+m
    const float if0 = exp2f(-(float)m * 0.4152410118609203f);
    const float if1 = exp2f(-(float)(16 + m) * 0.4152410118609203f);
#pragma unroll
    for (int i = 0; i < 4; ++i) {
#pragma unroll
      for (int r = 0; r < 4; ++r) {
        const int ridx = wr * 64 + i * 16 + quad * 4 + r;
        const int row = rowBase + ridx;
        const float rn = rsqrtf((ssbuf[0][ridx] + ssbuf[1][ridx]) * (1.f / 128.f) + 1e-6f);
        float v0 = acc[i][0][r] * rn, v1 = acc[i][1][r] * rn;
        float v2 = acc[i][2][r] * rn, v3 = acc[i][3][r] * rn;
        float o0 = v0, o1 = v1, o2 = v2, o3 = v3;
        if (wc == 0) {  // cols 0..63 of head: rotate pairs (d, d+32)
          const float t = (float)(row & (T_ - 1));
          const float a0 = t * if0, a1 = t * if1;
          const float c0_ = cosf(a0), s0_ = sinf(a0);
          const float c1_ = cosf(a1), s1_ = sinf(a1);
          o0 = v0 * c0_ - v2 * s0_;
          o1 = v1 * c1_ - v3 * s1_;
          o2 = v2 * c0_ + v0 * s0_;
          o3 = v3 * c1_ + v1 * s1_;
        }
        bf16_t* out = qkv + (size_t)row * QKV_ + colBase + wc * 64 + m;
        out[0]  = (bf16_t)(o0 * g);
        out[16] = (bf16_t)(o1 * g);
        out[32] = (bf16_t)(o2 * g);
        out[48] = (bf16_t)(o3 * g);
      }
    }
  } else {
    // ---- v epilogue: raw row-major store + transposed store into vt
    const int kvh = bx - 20;
#pragma unroll
    for (int i = 0; i < 4; ++i)
#pragma unroll
      for (int j = 0; j < 4; ++j) {
        const int row0 = rowBase + wr * 64 + i * 16 + quad * 4;
        const int d = wc * 64 + j * 16 + m;
        bf16x4 pv;
#pragma unroll
        for (int r = 0; r < 4; ++r) {
          pv[r] = (bf16_t)acc[i][j][r];
          qkv[(size_t)(row0 + r) * QKV_ + colBase + d] = pv[r];
        }
        const int b = row0 >> 11, t0 = row0 & (T_ - 1);
        *(bf16x4*)(vt + ((size_t)(b * KVH_ + kvh) * HD_ + d) * T_ + t0) = pv;
      }
  }
}

// ---------------------------------------------------------------------------
// Flash attention, S^T formulation, software-pipelined. R4 (unchanged):
//  * NO-MAX softmax: q,k are RMS-normalized (RoPE = rotation, gain=1), so
//    |S| <= 128*QSCALE = 16.4 log2-units. exp2(S) <= 8.2e4, l <= 1.7e8 --
//    safely inside f32, and bf16 P has scale-invariant relative error.
//    Masked entries: S=-1e30 -> exp2 underflows to exactly 0.
//  * grid (8,16,4): block handles q-tiles {15-x, x} -> uniform 68 iters.
// 4 waves x 32 q-rows. K-step 32, double-buffered K/V LDS via
// global_load_lds. LDS read offsets hoisted out of the K-loop.
// ---------------------------------------------------------------------------
__global__ __launch_bounds__(256) void attn_kernel(const bf16_t* __restrict__ qkv,
                                                   const bf16_t* __restrict__ vt,
                                                   bf16_t* __restrict__ y) {
  __shared__ __align__(16) bf16_t Ks[2][32 * 128];  // [key][hd], chunk slot s holds src chunk s^(key&15)
  __shared__ __align__(16) bf16_t Vs[2][128 * 32];  // [d][key], slot c holds src chunk c^((d^(d>>2))&3)
  __shared__ __align__(16) bf16_t Ps[4][32 * 40];   // per-wave P [qrow][key], stride 40

  const int tid = threadIdx.x;
  const int w = tid >> 6, lane = tid & 63;
  const int m = lane & 15, q = lane >> 4;
  const int h = blockIdx.y, b = blockIdx.z, kvh = h >> 2;

  const bf16_t* qptr = qkv + (size_t)(b * T_) * QKV_ + h * HD_;
  const bf16_t* kptr = qkv + (size_t)(b * T_) * QKV_ + DIM_ + kvh * HD_;
  const bf16_t* vptr = qkv + (size_t)(b * T_) * QKV_ + DIM_ + KVH_ * HD_ + kvh * HD_;
  const bf16_t* vtptr = vt + (size_t)(b * KVH_ + kvh) * HD_ * T_;

  // per-thread staging indices (fixed): K 512 chunks, V 512 chunks
  const int kKey0 = tid >> 4, kC0 = tid & 15;
  const int kKey1 = (256 + tid) >> 4, kC1 = tid & 15;
  const int vD0 = tid >> 2, vC0 = tid & 3;
  const int vD1 = (256 + tid) >> 2, vC1 = tid & 3;
  const int vS0 = (vD0 ^ (vD0 >> 2)) & 3, vS1 = (vD1 ^ (vD1 >> 2)) & 3;

  // hoisted LDS read offsets (loop-invariant; elements)
  int koff[2][4], voff[8], poff[2];
#pragma unroll
  for (int kf = 0; kf < 2; ++kf)
#pragma unroll
    for (int c = 0; c < 4; ++c)
      koff[kf][c] = (kf * 16 + m) * 128 + (((c * 4 + q) ^ m) & 15) * 8;
#pragma unroll
  for (int f = 0; f < 8; ++f) {
    const int d = f * 16 + m;
    voff[f] = d * 32 + ((q ^ ((d ^ (d >> 2)) & 3)) & 3) * 8;
  }
#pragma unroll
  for (int qf = 0; qf < 2; ++qf) poff[qf] = (qf * 16 + m) * 40 + q * 8;

#pragma unroll 1
  for (int ti = 0; ti < 2; ++ti) {
    const int qb = ((ti == 0) ? (15 - (int)blockIdx.x) : (int)blockIdx.x) * 128;
    const int qbw = qb + w * 32;
    const int nk = (qb >> 5) + 4;

    // Q fragments (B-operand): aq[qf][c] = Q[qbw+qf*16+m][c*32+q*8 ..+8]
    bf16x8 aq[2][4];
#pragma unroll
    for (int qf = 0; qf < 2; ++qf)
#pragma unroll
      for (int c = 0; c < 4; ++c)
        aq[qf][c] = *(const bf16x8*)(qptr + (size_t)(qbw + qf * 16 + m) * QKV_ + c * 32 + q * 8);

    f32x4 o[2][8];
#pragma unroll
    for (int qf = 0; qf < 2; ++qf)
#pragma unroll
      for (int f = 0; f < 8; ++f) o[qf][f] = (f32x4){0.f, 0.f, 0.f, 0.f};
    float l_r[2] = {0.f, 0.f};

    // prefetch tile 0 (elem offset = chunk_id * 8)
    {
      gload16(kptr + (size_t)kKey0 * QKV_ + ((kC0 ^ kKey0) & 15) * 8, &Ks[0][tid * 8]);
      gload16(kptr + (size_t)kKey1 * QKV_ + ((kC1 ^ kKey1) & 15) * 8, &Ks[0][(256 + tid) * 8]);
      gload16(vtptr + (size_t)vD0 * T_ + (vC0 ^ vS0) * 8, &Vs[0][tid * 8]);
      gload16(vtptr + (size_t)vD1 * T_ + (vC1 ^ vS1) * 8, &Vs[0][(256 + tid) * 8]);
    }

#pragma unroll 1
    for (int it = 0; it < nk; ++it) {
      const int kb = it << 5;
      __syncthreads();  // drains tile-it loads (issued one full iter ago)

      if (it + 1 < nk) {  // issue tile it+1 into the other buffer
        const int kb2 = kb + 32;
        bf16_t* Kb = Ks[(it + 1) & 1];
        bf16_t* Vb = Vs[(it + 1) & 1];
        gload16(kptr + (size_t)(kb2 + kKey0) * QKV_ + ((kC0 ^ kKey0) & 15) * 8, &Kb[tid * 8]);
        gload16(kptr + (size_t)(kb2 + kKey1) * QKV_ + ((kC1 ^ kKey1) & 15) * 8, &Kb[(256 + tid) * 8]);
        gload16(vtptr + (size_t)vD0 * T_ + kb2 + (vC0 ^ vS0) * 8, &Vb[tid * 8]);
        gload16(vtptr + (size_t)vD1 * T_ + kb2 + (vC1 ^ vS1) * 8, &Vb[(256 + tid) * 8]);
      }

      if (kb > qbw + 31) continue;  // whole key-tile masked for this wave
      const bf16_t* Kb = Ks[it & 1];
      const bf16_t* Vb = Vs[it & 1];

      // ---- S^T = K . Q^T   (16 MFMA, 8 ds_read_b128)
      f32x4 S[2][2];
#pragma unroll
      for (int qf = 0; qf < 2; ++qf)
#pragma unroll
        for (int kf = 0; kf < 2; ++kf) S[qf][kf] = (f32x4){0.f, 0.f, 0.f, 0.f};
#pragma unroll
      for (int kf = 0; kf < 2; ++kf)
#pragma unroll
        for (int c = 0; c < 4; ++c) {
          bf16x8 ak = *(const bf16x8*)&Kb[koff[kf][c]];
          S[0][kf] = __builtin_amdgcn_mfma_f32_16x16x32_bf16(ak, aq[0][c], S[0][kf], 0, 0, 0);
          S[1][kf] = __builtin_amdgcn_mfma_f32_16x16x32_bf16(ak, aq[1][c], S[1][kf], 0, 0, 0);
        }

      const bool needmask = (kb + 31) > qbw;
#pragma unroll
      for (int qf = 0; qf < 2; ++qf) {
        const int qrow = qbw + qf * 16 + m;
        if (needmask) {
#pragma unroll
          for (int kf = 0; kf < 2; ++kf)
#pragma unroll
            for (int r = 0; r < 4; ++r) {
              int key = kb + kf * 16 + q * 4 + r;
              if (key > qrow) S[qf][kf][r] = -1e30f;
            }
        }
        // no-max softmax: p = exp2(S) directly (scores bounded, see header)
        float rs = 0.f;
#pragma unroll
        for (int kf = 0; kf < 2; ++kf)
#pragma unroll
          for (int r = 0; r < 4; ++r) {
            float p = exp2f(S[qf][kf][r]);
            S[qf][kf][r] = p;
            rs += p;
          }
        rs += __shfl_xor(rs, 16);
        rs += __shfl_xor(rs, 32);
        l_r[qf] += rs;
#pragma unroll
        for (int kf = 0; kf < 2; ++kf) {
          bf16x4 pk = {(__bf16)S[qf][kf][0], (__bf16)S[qf][kf][1],
                       (__bf16)S[qf][kf][2], (__bf16)S[qf][kf][3]};
          *(bf16x4*)&Ps[w][(qf * 16 + m) * 40 + kf * 16 + q * 4] = pk;
        }
      }
      asm volatile("s_waitcnt lgkmcnt(0)" ::: "memory");

      // ---- PV: O^T += V^T . P^T  (16 MFMA, 10 ds_read_b128)
      bf16x8 Pb[2];
#pragma unroll
      for (int qf = 0; qf < 2; ++qf)
        Pb[qf] = *(const bf16x8*)&Ps[w][poff[qf]];
#pragma unroll
      for (int f = 0; f < 8; ++f) {
        bf16x8 av = *(const bf16x8*)&Vb[voff[f]];
        o[0][f] = __builtin_amdgcn_mfma_f32_16x16x32_bf16(av, Pb[0], o[0][f], 0, 0, 0);
        o[1][f] = __builtin_amdgcn_mfma_f32_16x16x32_bf16(av, Pb[1], o[1][f], 0, 0, 0);
      }
    }

    // ---- epilogue: y = o/l minus projection onto normalized v row
#pragma unroll
    for (int qf = 0; qf < 2; ++qf) {
      const int trow = qbw + qf * 16 + m;
      const float linv = 1.f / l_r[qf];
      bf16x4 vv[8];
      float n2 = 0.f, dp = 0.f;
#pragma unroll
      for (int f = 0; f < 8; ++f) {
        vv[f] = *(const bf16x4*)(vptr + (size_t)trow * QKV_ + f * 16 + q * 4);
#pragma unroll
        for (int r = 0; r < 4; ++r) {
          float v = (float)vv[f][r];
          n2 += v * v;
          dp += o[qf][f][r] * linv * v;
        }
      }
      n2 += __shfl_xor(n2, 16); n2 += __shfl_xor(n2, 32);
      dp += __shfl_xor(dp, 16); dp += __shfl_xor(dp, 32);
      float d = fmaxf(sqrtf(n2), 1e-12f);
      float coef = dp / (d * d);
#pragma unroll
      for (int f = 0; f < 8; ++f) {
        bf16x4 yo;
#pragma unroll
        for (int r = 0; r < 4; ++r)
          yo[r] = (bf16_t)(o[qf][f][r] * linv - coef * (float)vv[f][r]);
        *(bf16x4*)(y + (size_t)(b * T_ + trow) * DIM_ + h * HD_ + f * 16 + q * 4) = yo;
      }
    }
    __syncthreads();  // protect K/V buffers before next q-tile's prefetch
  }
}

// ---------------------------------------------------------------------------
extern "C" void kernel_launch(void* const* d_in, const int* in_sizes, int n_in,
                              void* d_out, int out_size, void* d_ws, size_t ws_size,
                              hipStream_t stream) {
  const float* x = (const float*)d_in[0];
  const float* Wq = (const float*)d_in[1];
  const float* Wk = (const float*)d_in[2];
  const float* Wv = (const float*)d_in[3];
  const float* Wp = (const float*)d_in[4];
  const float* qg = (const float*)d_in[5];

  bf16_t* xbf = (bf16_t*)d_ws;                        // 8192*2048
  bf16_t* wqkv = xbf + (size_t)8192 * 2048;           // 3072*2048
  bf16_t* wproj = wqkv + (size_t)3072 * 2048;         // 2048*2048
  bf16_t* qkv = wproj + (size_t)2048 * 2048;          // 8192*3072
  bf16_t* vt = qkv + (size_t)8192 * 3072;             // 16*128*2048
  bf16_t* ybf = xbf;                                  // reuse after gemm_qkv

  cvt_all<<<26624, 256, 0, stream>>>((const float4*)x, (const float4*)Wq,
                                     (const float4*)Wk, (const float4*)Wv,
                                     (const float4*)Wp, (bf16x4*)xbf,
                                     (bf16x4*)wqkv, (bf16x4*)wproj);
  gemm_qkv<<<dim3(24, 64), 256, 0, stream>>>(xbf, wqkv, qkv, vt, qg);
  attn_kernel<<<dim3(8, 16, 4), 256, 0, stream>>>(qkv, vt, ybf);
  gemm_bt<<<dim3(16, 64), 256, 0, stream>>>(ybf, wproj, d_out, 8192, 2048, 2048, 0);
}

// Round 6
// 546.900 us; speedup vs baseline: 1.0456x; 1.0456x over previous
//
#include <hip/hip_runtime.h>
#include <cstdint>
#include <cstddef>

typedef __bf16 bf16_t;
typedef __bf16 bf16x4 __attribute__((ext_vector_type(4)));
typedef __bf16 bf16x8 __attribute__((ext_vector_type(8)));
typedef float f32x4 __attribute__((ext_vector_type(4)));

#define B_ 4
#define T_ 2048
#define DIM_ 2048
#define H_ 16
#define KVH_ 4
#define HD_ 128
#define QKV_ 3072
// SCALE * log2(e): folded into q rows in the gemm_qkv epilogue; attn uses exp2.
#define QSCALE (0.08838834764831845f * 1.4426950408889634f)

// ---------------------------------------------------------------------------
// async global->LDS, 16B per lane. LDS dest = wave-uniform base + lane*16B.
// Dest pointer arithmetic is in ELEMENTS: 8 bf16 = 16B per lane.
// ---------------------------------------------------------------------------
__device__ __forceinline__ void gload16(const bf16_t* g, bf16_t* l) {
  __builtin_amdgcn_global_load_lds(
      (const __attribute__((address_space(1))) unsigned int*)g,
      (__attribute__((address_space(3))) unsigned int*)l, 16, 0, 0);
}

// ---------------------------------------------------------------------------
// fused fp32 -> bf16 convert for all five inputs (one launch).
// Segments (float4 units): x 4194304 | Wq 1048576 | Wk 262144 | Wv 262144 | Wp 1048576
// ---------------------------------------------------------------------------
__global__ __launch_bounds__(256) void cvt_all(const float4* __restrict__ x,
                                               const float4* __restrict__ wq,
                                               const float4* __restrict__ wk,
                                               const float4* __restrict__ wv,
                                               const float4* __restrict__ wp,
                                               bf16x4* __restrict__ xb,
                                               bf16x4* __restrict__ wqkvb,
                                               bf16x4* __restrict__ wpb) {
  int i = blockIdx.x * 256 + threadIdx.x;
  const float4* s;
  bf16x4* dst;
  int off;
  if (i < 4194304) { s = x; dst = xb; off = i; }
  else if (i < 5242880) { s = wq; dst = wqkvb; off = i - 4194304; }
  else if (i < 5505024) { s = wk; dst = wqkvb + 1048576; off = i - 5242880; }
  else if (i < 5767168) { s = wv; dst = wqkvb + 1310720; off = i - 5505024; }
  else { s = wp; dst = wpb; off = i - 5767168; }
  float4 v = s[off];
  bf16x4 o = {(__bf16)v.x, (__bf16)v.y, (__bf16)v.z, (__bf16)v.w};
  dst[off] = o;
}

// ---------------------------------------------------------------------------
// R6: 8-phase 256x256xBK64 GEMM (C = A @ B^T, bf16 in, fp32/bf16 out).
// Port of the learn_hip m201 template (T3+T4+T5): 8 waves (2Mx4N), 512 thr,
// 128 KiB LDS double-buffer, per-wave output 128x64 (acc[8][4] f32x4).
// LDS layout per tile: [kk-half][256 rows][32 K] bf16 so each stage group
// (A-kk0 | B-kk0 | A-kk1 | B-kk1; 2 global_load_lds per thread each) is a
// contiguous 16 KiB block -> counted vmcnt(4) at mid-tile and boundary,
// NEVER vmcnt(0) in the steady loop (T4). Chunk swizzle: read chunk
// q4^(row&3); staged via pre-swizzled GLOBAL source (linear LDS dest,
// rule: both-sides-or-neither). 4 phases per K-tile, each:
// {stage 1 group | ds_read 4-8 b128 | s_barrier | lgkmcnt(0)+sched_barrier |
//  setprio(1) 16 MFMA setprio(0) | [vmcnt(4)] s_barrier}.
// In-flight accounting (per wave, 2 loads/group): at P1.vmcnt: {Akk1(t),
// Bkk1(t), Akk0(t+1), Bkk0(t+1)} = 8 -> wait 4 oldest = kk1(t) landed for
// P2/P3. At P3.vmcnt: kk0(t+1) landed for next tile's P0. Barrier after
// each vmcnt unions the per-wave guarantees across all 8 waves.
// ---------------------------------------------------------------------------
#define STAGE2(gsrc, ldst)                                   \
  do {                                                       \
    gload16((gsrc), (ldst) + tid * 8);                       \
    gload16((gsrc) + (size_t)128 * K, (ldst) + 4096 + tid * 8); \
  } while (0)

__global__ __launch_bounds__(512, 2) void gemm_bt(const bf16_t* __restrict__ A,
                                                  const bf16_t* __restrict__ B,
                                                  void* __restrict__ Cp,
                                                  int M, int N, int K, int out_bf16) {
  __shared__ __align__(16) bf16_t Ab[2 * 16384];  // [buf][kk][256][32]
  __shared__ __align__(16) bf16_t Bb[2 * 16384];
  const int tid = threadIdx.x;
  const int w = tid >> 6, lane = tid & 63;
  const int m16 = lane & 15, q4 = lane >> 4;
  const int wr = w >> 2, wc = w & 3;
  const int rowBase = blockIdx.y * 256, colBase = blockIdx.x * 256;

  // staging: thread handles chunks (row=tid>>2, kc=tid&3) and (+128 rows).
  // physical slot (row,kc) holds logical chunk kc^(row&3) -> pre-swizzled src.
  const int srow = tid >> 2, skc = tid & 3;
  const bf16_t* srcA = A + (size_t)(rowBase + srow) * K + (skc ^ (srow & 3)) * 8;
  const bf16_t* srcB = B + (size_t)(colBase + srow) * K + (skc ^ (srow & 3)) * 8;

  // fragment read offsets (elements): row R = wr*128 + mi*16 + m16,
  // chunk = q4 ^ (R&3) = q4 ^ (m16&3); elem = kk*8192 + R*32 + chunk*8.
  const int cs = (q4 ^ m16) & 3;
  const int aoff = wr * 4096 + m16 * 32 + cs * 8;
  const int boff = wc * 2048 + m16 * 32 + cs * 8;

  f32x4 acc[8][4];
#pragma unroll
  for (int i = 0; i < 8; ++i)
#pragma unroll
    for (int j = 0; j < 4; ++j) acc[i][j] = (f32x4){0.f, 0.f, 0.f, 0.f};

  const int nt = K >> 6;
  // prologue: stage all 4 groups of tile 0 into buffer 0
  STAGE2(srcA, Ab);
  STAGE2(srcB, Bb);
  STAGE2(srcA + 32, Ab + 8192);
  STAGE2(srcB + 32, Bb + 8192);
  asm volatile("s_waitcnt vmcnt(4)" ::: "memory");  // kk0 groups landed
  __builtin_amdgcn_s_barrier();

#pragma unroll 1
  for (int t = 0; t < nt; ++t) {
    const int cb = (t & 1) << 14, nb = cb ^ 16384;
    const int pk = ((t + 1 < nt) ? t + 1 : t) << 6;  // clamped prefetch K-base
    const bf16_t* Ac = Ab + cb + aoff;
    const bf16_t* Bc = Bb + cb + boff;
    bf16x8 a[4], b[4];

    // ---- P0: stage A-kk0(t+1); read kk0 mi0-3 + B-kk0; MFMA acc[0..3][*]
    STAGE2(srcA + pk, Ab + nb);
#pragma unroll
    for (int i = 0; i < 4; ++i) a[i] = *(const bf16x8*)(Ac + i * 512);
#pragma unroll
    for (int j = 0; j < 4; ++j) b[j] = *(const bf16x8*)(Bc + j * 512);
    __builtin_amdgcn_s_barrier();
    asm volatile("s_waitcnt lgkmcnt(0)" ::: "memory");
    __builtin_amdgcn_sched_barrier(0);
    __builtin_amdgcn_s_setprio(1);
#pragma unroll
    for (int i = 0; i < 4; ++i)
#pragma unroll
      for (int j = 0; j < 4; ++j)
        acc[i][j] = __builtin_amdgcn_mfma_f32_16x16x32_bf16(a[i], b[j], acc[i][j], 0, 0, 0);
    __builtin_amdgcn_s_setprio(0);
    __builtin_amdgcn_s_barrier();

    // ---- P1: stage B-kk0(t+1); read kk0 mi4-7; MFMA acc[4..7][*]
    STAGE2(srcB + pk, Bb + nb);
#pragma unroll
    for (int i = 0; i < 4; ++i) a[i] = *(const bf16x8*)(Ac + (4 + i) * 512);
    __builtin_amdgcn_s_barrier();
    asm volatile("s_waitcnt lgkmcnt(0)" ::: "memory");
    __builtin_amdgcn_sched_barrier(0);
    __builtin_amdgcn_s_setprio(1);
#pragma unroll
    for (int i = 0; i < 4; ++i)
#pragma unroll
      for (int j = 0; j < 4; ++j)
        acc[4 + i][j] = __builtin_amdgcn_mfma_f32_16x16x32_bf16(a[i], b[j], acc[4 + i][j], 0, 0, 0);
    __builtin_amdgcn_s_setprio(0);
    asm volatile("s_waitcnt vmcnt(4)" ::: "memory");  // kk1(t) landed
    __builtin_amdgcn_s_barrier();

    // ---- P2: stage A-kk1(t+1); read kk1 mi0-3 + B-kk1; MFMA acc[0..3][*]
    STAGE2(srcA + pk + 32, Ab + nb + 8192);
#pragma unroll
    for (int i = 0; i < 4; ++i) a[i] = *(const bf16x8*)(Ac + 8192 + i * 512);
#pragma unroll
    for (int j = 0; j < 4; ++j) b[j] = *(const bf16x8*)(Bc + 8192 + j * 512);
    __builtin_amdgcn_s_barrier();
    asm volatile("s_waitcnt lgkmcnt(0)" ::: "memory");
    __builtin_amdgcn_sched_barrier(0);
    __builtin_amdgcn_s_setprio(1);
#pragma unroll
    for (int i = 0; i < 4; ++i)
#pragma unroll
      for (int j = 0; j < 4; ++j)
        acc[i][j] = __builtin_amdgcn_mfma_f32_16x16x32_bf16(a[i], b[j], acc[i][j], 0, 0, 0);
    __builtin_amdgcn_s_setprio(0);
    __builtin_amdgcn_s_barrier();

    // ---- P3: stage B-kk1(t+1); read kk1 mi4-7; MFMA acc[4..7][*]
    STAGE2(srcB + pk + 32, Bb + nb + 8192);
#pragma unroll
    for (int i = 0; i < 4; ++i) a[i] = *(const bf16x8*)(Ac + 8192 + (4 + i) * 512);
    __builtin_amdgcn_s_barrier();
    asm volatile("s_waitcnt lgkmcnt(0)" ::: "memory");
    __builtin_amdgcn_sched_barrier(0);
    __builtin_amdgcn_s_setprio(1);
#pragma unroll
    for (int i = 0; i < 4; ++i)
#pragma unroll
      for (int j = 0; j < 4; ++j)
        acc[4 + i][j] = __builtin_amdgcn_mfma_f32_16x16x32_bf16(a[i], b[j], acc[4 + i][j], 0, 0, 0);
    __builtin_amdgcn_s_setprio(0);
    asm volatile("s_waitcnt vmcnt(4)" ::: "memory");  // kk0(t+1) landed
    __builtin_amdgcn_s_barrier();
  }

  // ---- epilogue: C write. row <- (wr,mi,q4,r), col <- (wc,ni,m16)
  if (out_bf16) {
    bf16_t* C = (bf16_t*)Cp;
#pragma unroll
    for (int i = 0; i < 8; ++i)
#pragma unroll
      for (int j = 0; j < 4; ++j)
#pragma unroll
        for (int r = 0; r < 4; ++r) {
          int row = rowBase + wr * 128 + i * 16 + q4 * 4 + r;
          int col = colBase + wc * 64 + j * 16 + m16;
          C[(size_t)row * N + col] = (bf16_t)acc[i][j][r];
        }
  } else {
    float* C = (float*)Cp;
#pragma unroll
    for (int i = 0; i < 8; ++i)
#pragma unroll
      for (int j = 0; j < 4; ++j)
#pragma unroll
        for (int r = 0; r < 4; ++r) {
          int row = rowBase + wr * 128 + i * 16 + q4 * 4 + r;
          int col = colBase + wc * 64 + j * 16 + m16;
          C[(size_t)row * N + col] = acc[i][j][r];
        }
  }
}

// ---------------------------------------------------------------------------
// QKV GEMM with fused epilogue: M=8192, N=3072, K=2048. EXACT R4 structure
// (measured 206us; R5's explicit dbuf was neutral -> reverted).
// Col-tile bx: 0..15 = q heads, 16..19 = k heads, 20..23 = v heads.
// q/k tiles: RMSNorm (fp32 acc, cross-wave LDS reduce) + RoPE (+gain*QSCALE
// for q). v tiles: raw store + transposed store into vt (B,KVH,HD,T).
// ---------------------------------------------------------------------------
__global__ __launch_bounds__(256) void gemm_qkv(const bf16_t* __restrict__ A,
                                                const bf16_t* __restrict__ Bw,
                                                bf16_t* __restrict__ qkv,
                                                bf16_t* __restrict__ vt,
                                                const float* __restrict__ gain) {
  __shared__ bf16_t As[128 * 32];
  __shared__ bf16_t Bs[128 * 32];
  __shared__ float ssbuf[2][128];
  const int tid = threadIdx.x;
  const int w = tid >> 6, lane = tid & 63;
  const int m = lane & 15, quad = lane >> 4;
  const int wr = w >> 1, wc = w & 1;
  const int rowBase = blockIdx.y * 128, colBase = blockIdx.x * 128;

  f32x4 acc[4][4];
#pragma unroll
  for (int i = 0; i < 4; ++i)
#pragma unroll
    for (int j = 0; j < 4; ++j) acc[i][j] = (f32x4){0.f, 0.f, 0.f, 0.f};

  for (int kk = 0; kk < 64; ++kk) {
    const int k0 = kk << 5;
#pragma unroll
    for (int i2 = 0; i2 < 2; ++i2) {
      int idx = i2 * 256 + tid;
      int row = idx >> 2, kc = idx & 3;
      gload16(A + (size_t)(rowBase + row) * 2048 + k0 + kc * 8, &As[idx * 8]);
      gload16(Bw + (size_t)(colBase + row) * 2048 + k0 + kc * 8, &Bs[idx * 8]);
    }
    __syncthreads();
    bf16x8 a[4], bb[4];
#pragma unroll
    for (int i = 0; i < 4; ++i)
      a[i] = *(const bf16x8*)&As[(wr * 64 + i * 16 + m) * 32 + quad * 8];
#pragma unroll
    for (int j = 0; j < 4; ++j)
      bb[j] = *(const bf16x8*)&Bs[(wc * 64 + j * 16 + m) * 32 + quad * 8];
#pragma unroll
    for (int i = 0; i < 4; ++i)
#pragma unroll
      for (int j = 0; j < 4; ++j)
        acc[i][j] = __builtin_amdgcn_mfma_f32_16x16x32_bf16(a[i], bb[j], acc[i][j], 0, 0, 0);
    __syncthreads();
  }

  const int bx = blockIdx.x;
  if (bx < 20) {
    // ---- q/k epilogue: RMSNorm + RoPE
    const float g = (bx < 16) ? gain[bx] * QSCALE : 1.0f;
#pragma unroll
    for (int i = 0; i < 4; ++i) {
      float ssp[4];
#pragma unroll
      for (int r = 0; r < 4; ++r) {
        float s = 0.f;
#pragma unroll
        for (int j = 0; j < 4; ++j) s += acc[i][j][r] * acc[i][j][r];
#pragma unroll
        for (int off = 1; off <= 8; off <<= 1) s += __shfl_xor(s, off);
        ssp[r] = s;
      }
      if (m == 0) {
#pragma unroll
        for (int r = 0; r < 4; ++r) ssbuf[wc][wr * 64 + i * 16 + quad * 4 + r] = ssp[r];
      }
    }
    __syncthreads();
    const float if0 = exp2f(-(float)m * 0.4152410118609203f);
    const float if1 = exp2f(-(float)(16 + m) * 0.4152410118609203f);
#pragma unroll
    for (int i = 0; i < 4; ++i) {
#pragma unroll
      for (int r = 0; r < 4; ++r) {
        const int ridx = wr * 64 + i * 16 + quad * 4 + r;
        const int row = rowBase + ridx;
        const float rn = rsqrtf((ssbuf[0][ridx] + ssbuf[1][ridx]) * (1.f / 128.f) + 1e-6f);
        float v0 = acc[i][0][r] * rn, v1 = acc[i][1][r] * rn;
        float v2 = acc[i][2][r] * rn, v3 = acc[i][3][r] * rn;
        float o0 = v0, o1 = v1, o2 = v2, o3 = v3;
        if (wc == 0) {  // cols 0..63 of head: rotate pairs (d, d+32)
          const float t = (float)(row & (T_ - 1));
          const float a0 = t * if0, a1 = t * if1;
          const float c0_ = cosf(a0), s0_ = sinf(a0);
          const float c1_ = cosf(a1), s1_ = sinf(a1);
          o0 = v0 * c0_ - v2 * s0_;
          o1 = v1 * c1_ - v3 * s1_;
          o2 = v2 * c0_ + v0 * s0_;
          o3 = v3 * c1_ + v1 * s1_;
        }
        bf16_t* out = qkv + (size_t)row * QKV_ + colBase + wc * 64 + m;
        out[0]  = (bf16_t)(o0 * g);
        out[16] = (bf16_t)(o1 * g);
        out[32] = (bf16_t)(o2 * g);
        out[48] = (bf16_t)(o3 * g);
      }
    }
  } else {
    // ---- v epilogue: raw row-major store + transposed store into vt
    const int kvh = bx - 20;
#pragma unroll
    for (int i = 0; i < 4; ++i)
#pragma unroll
      for (int j = 0; j < 4; ++j) {
        const int row0 = rowBase + wr * 64 + i * 16 + quad * 4;
        const int d = wc * 64 + j * 16 + m;
        bf16x4 pv;
#pragma unroll
        for (int r = 0; r < 4; ++r) {
          pv[r] = (bf16_t)acc[i][j][r];
          qkv[(size_t)(row0 + r) * QKV_ + colBase + d] = pv[r];
        }
        const int b = row0 >> 11, t0 = row0 & (T_ - 1);
        *(bf16x4*)(vt + ((size_t)(b * KVH_ + kvh) * HD_ + d) * T_ + t0) = pv;
      }
  }
}

// ---------------------------------------------------------------------------
// Flash attention, S^T formulation, software-pipelined (unchanged from R4):
// NO-MAX softmax (scores bounded: |S| <= 16.4 log2u), grid (8,16,4) with
// paired q-tiles {15-x, x} (uniform 68 iters/block). 4 waves x 32 q-rows.
// K-step 32, double-buffered K/V LDS via global_load_lds.
// ---------------------------------------------------------------------------
__global__ __launch_bounds__(256) void attn_kernel(const bf16_t* __restrict__ qkv,
                                                   const bf16_t* __restrict__ vt,
                                                   bf16_t* __restrict__ y) {
  __shared__ __align__(16) bf16_t Ks[2][32 * 128];
  __shared__ __align__(16) bf16_t Vs[2][128 * 32];
  __shared__ __align__(16) bf16_t Ps[4][32 * 40];

  const int tid = threadIdx.x;
  const int w = tid >> 6, lane = tid & 63;
  const int m = lane & 15, q = lane >> 4;
  const int h = blockIdx.y, b = blockIdx.z, kvh = h >> 2;

  const bf16_t* qptr = qkv + (size_t)(b * T_) * QKV_ + h * HD_;
  const bf16_t* kptr = qkv + (size_t)(b * T_) * QKV_ + DIM_ + kvh * HD_;
  const bf16_t* vptr = qkv + (size_t)(b * T_) * QKV_ + DIM_ + KVH_ * HD_ + kvh * HD_;
  const bf16_t* vtptr = vt + (size_t)(b * KVH_ + kvh) * HD_ * T_;

  const int kKey0 = tid >> 4, kC0 = tid & 15;
  const int kKey1 = (256 + tid) >> 4, kC1 = tid & 15;
  const int vD0 = tid >> 2, vC0 = tid & 3;
  const int vD1 = (256 + tid) >> 2, vC1 = tid & 3;
  const int vS0 = (vD0 ^ (vD0 >> 2)) & 3, vS1 = (vD1 ^ (vD1 >> 2)) & 3;

  int koff[2][4], voff[8], poff[2];
#pragma unroll
  for (int kf = 0; kf < 2; ++kf)
#pragma unroll
    for (int c = 0; c < 4; ++c)
      koff[kf][c] = (kf * 16 + m) * 128 + (((c * 4 + q) ^ m) & 15) * 8;
#pragma unroll
  for (int f = 0; f < 8; ++f) {
    const int d = f * 16 + m;
    voff[f] = d * 32 + ((q ^ ((d ^ (d >> 2)) & 3)) & 3) * 8;
  }
#pragma unroll
  for (int qf = 0; qf < 2; ++qf) poff[qf] = (qf * 16 + m) * 40 + q * 8;

#pragma unroll 1
  for (int ti = 0; ti < 2; ++ti) {
    const int qb = ((ti == 0) ? (15 - (int)blockIdx.x) : (int)blockIdx.x) * 128;
    const int qbw = qb + w * 32;
    const int nk = (qb >> 5) + 4;

    bf16x8 aq[2][4];
#pragma unroll
    for (int qf = 0; qf < 2; ++qf)
#pragma unroll
      for (int c = 0; c < 4; ++c)
        aq[qf][c] = *(const bf16x8*)(qptr + (size_t)(qbw + qf * 16 + m) * QKV_ + c * 32 + q * 8);

    f32x4 o[2][8];
#pragma unroll
    for (int qf = 0; qf < 2; ++qf)
#pragma unroll
      for (int f = 0; f < 8; ++f) o[qf][f] = (f32x4){0.f, 0.f, 0.f, 0.f};
    float l_r[2] = {0.f, 0.f};

    {
      gload16(kptr + (size_t)kKey0 * QKV_ + ((kC0 ^ kKey0) & 15) * 8, &Ks[0][tid * 8]);
      gload16(kptr + (size_t)kKey1 * QKV_ + ((kC1 ^ kKey1) & 15) * 8, &Ks[0][(256 + tid) * 8]);
      gload16(vtptr + (size_t)vD0 * T_ + (vC0 ^ vS0) * 8, &Vs[0][tid * 8]);
      gload16(vtptr + (size_t)vD1 * T_ + (vC1 ^ vS1) * 8, &Vs[0][(256 + tid) * 8]);
    }

#pragma unroll 1
    for (int it = 0; it < nk; ++it) {
      const int kb = it << 5;
      __syncthreads();

      if (it + 1 < nk) {
        const int kb2 = kb + 32;
        bf16_t* Kb = Ks[(it + 1) & 1];
        bf16_t* Vb = Vs[(it + 1) & 1];
        gload16(kptr + (size_t)(kb2 + kKey0) * QKV_ + ((kC0 ^ kKey0) & 15) * 8, &Kb[tid * 8]);
        gload16(kptr + (size_t)(kb2 + kKey1) * QKV_ + ((kC1 ^ kKey1) & 15) * 8, &Kb[(256 + tid) * 8]);
        gload16(vtptr + (size_t)vD0 * T_ + kb2 + (vC0 ^ vS0) * 8, &Vb[tid * 8]);
        gload16(vtptr + (size_t)vD1 * T_ + kb2 + (vC1 ^ vS1) * 8, &Vb[(256 + tid) * 8]);
      }

      if (kb > qbw + 31) continue;
      const bf16_t* Kb = Ks[it & 1];
      const bf16_t* Vb = Vs[it & 1];

      f32x4 S[2][2];
#pragma unroll
      for (int qf = 0; qf < 2; ++qf)
#pragma unroll
        for (int kf = 0; kf < 2; ++kf) S[qf][kf] = (f32x4){0.f, 0.f, 0.f, 0.f};
#pragma unroll
      for (int kf = 0; kf < 2; ++kf)
#pragma unroll
        for (int c = 0; c < 4; ++c) {
          bf16x8 ak = *(const bf16x8*)&Kb[koff[kf][c]];
          S[0][kf] = __builtin_amdgcn_mfma_f32_16x16x32_bf16(ak, aq[0][c], S[0][kf], 0, 0, 0);
          S[1][kf] = __builtin_amdgcn_mfma_f32_16x16x32_bf16(ak, aq[1][c], S[1][kf], 0, 0, 0);
        }

      const bool needmask = (kb + 31) > qbw;
#pragma unroll
      for (int qf = 0; qf < 2; ++qf) {
        const int qrow = qbw + qf * 16 + m;
        if (needmask) {
#pragma unroll
          for (int kf = 0; kf < 2; ++kf)
#pragma unroll
            for (int r = 0; r < 4; ++r) {
              int key = kb + kf * 16 + q * 4 + r;
              if (key > qrow) S[qf][kf][r] = -1e30f;
            }
        }
        float rs = 0.f;
#pragma unroll
        for (int kf = 0; kf < 2; ++kf)
#pragma unroll
          for (int r = 0; r < 4; ++r) {
            float p = exp2f(S[qf][kf][r]);
            S[qf][kf][r] = p;
            rs += p;
          }
        rs += __shfl_xor(rs, 16);
        rs += __shfl_xor(rs, 32);
        l_r[qf] += rs;
#pragma unroll
        for (int kf = 0; kf < 2; ++kf) {
          bf16x4 pk = {(__bf16)S[qf][kf][0], (__bf16)S[qf][kf][1],
                       (__bf16)S[qf][kf][2], (__bf16)S[qf][kf][3]};
          *(bf16x4*)&Ps[w][(qf * 16 + m) * 40 + kf * 16 + q * 4] = pk;
        }
      }
      asm volatile("s_waitcnt lgkmcnt(0)" ::: "memory");

      bf16x8 Pb[2];
#pragma unroll
      for (int qf = 0; qf < 2; ++qf)
        Pb[qf] = *(const bf16x8*)&Ps[w][poff[qf]];
#pragma unroll
      for (int f = 0; f < 8; ++f) {
        bf16x8 av = *(const bf16x8*)&Vb[voff[f]];
        o[0][f] = __builtin_amdgcn_mfma_f32_16x16x32_bf16(av, Pb[0], o[0][f], 0, 0, 0);
        o[1][f] = __builtin_amdgcn_mfma_f32_16x16x32_bf16(av, Pb[1], o[1][f], 0, 0, 0);
      }
    }

#pragma unroll
    for (int qf = 0; qf < 2; ++qf) {
      const int trow = qbw + qf * 16 + m;
      const float linv = 1.f / l_r[qf];
      bf16x4 vv[8];
      float n2 = 0.f, dp = 0.f;
#pragma unroll
      for (int f = 0; f < 8; ++f) {
        vv[f] = *(const bf16x4*)(vptr + (size_t)trow * QKV_ + f * 16 + q * 4);
#pragma unroll
        for (int r = 0; r < 4; ++r) {
          float v = (float)vv[f][r];
          n2 += v * v;
          dp += o[qf][f][r] * linv * v;
        }
      }
      n2 += __shfl_xor(n2, 16); n2 += __shfl_xor(n2, 32);
      dp += __shfl_xor(dp, 16); dp += __shfl_xor(dp, 32);
      float d = fmaxf(sqrtf(n2), 1e-12f);
      float coef = dp / (d * d);
#pragma unroll
      for (int f = 0; f < 8; ++f) {
        bf16x4 yo;
#pragma unroll
        for (int r = 0; r < 4; ++r)
          yo[r] = (bf16_t)(o[qf][f][r] * linv - coef * (float)vv[f][r]);
        *(bf16x4*)(y + (size_t)(b * T_ + trow) * DIM_ + h * HD_ + f * 16 + q * 4) = yo;
      }
    }
    __syncthreads();
  }
}

// ---------------------------------------------------------------------------
extern "C" void kernel_launch(void* const* d_in, const int* in_sizes, int n_in,
                              void* d_out, int out_size, void* d_ws, size_t ws_size,
                              hipStream_t stream) {
  const float* x = (const float*)d_in[0];
  const float* Wq = (const float*)d_in[1];
  const float* Wk = (const float*)d_in[2];
  const float* Wv = (const float*)d_in[3];
  const float* Wp = (const float*)d_in[4];
  const float* qg = (const float*)d_in[5];

  bf16_t* xbf = (bf16_t*)d_ws;                        // 8192*2048
  bf16_t* wqkv = xbf + (size_t)8192 * 2048;           // 3072*2048
  bf16_t* wproj = wqkv + (size_t)3072 * 2048;         // 2048*2048
  bf16_t* qkv = wproj + (size_t)2048 * 2048;          // 8192*3072
  bf16_t* vt = qkv + (size_t)8192 * 3072;             // 16*128*2048
  bf16_t* ybf = xbf;                                  // reuse after gemm_qkv

  cvt_all<<<26624, 256, 0, stream>>>((const float4*)x, (const float4*)Wq,
                                     (const float4*)Wk, (const float4*)Wv,
                                     (const float4*)Wp, (bf16x4*)xbf,
                                     (bf16x4*)wqkv, (bf16x4*)wproj);
  gemm_qkv<<<dim3(24, 64), 256, 0, stream>>>(xbf, wqkv, qkv, vt, qg);
  attn_kernel<<<dim3(8, 16, 4), 256, 0, stream>>>(qkv, vt, ybf);
  gemm_bt<<<dim3(8, 32), 512, 0, stream>>>(ybf, wproj, d_out, 8192, 2048, 2048, 0);
}